// Round 2
// baseline (795.765 us; speedup 1.0000x reference)
//
#include <hip/hip_runtime.h>
#include <math.h>
#include <stdint.h>

// Problem constants: BS=16, SEQ=1024, NV=512, DM=256, K=8
#define BS 16
#define SEQ 1024
#define NV 512
#define DM 256
#define NK 8

// ---------------------------------------------------------------------------
// Module-global scratch. Every launch fully overwrites before reading
// (stream-ordered producer->consumer), so graph replay is self-contained.
// ---------------------------------------------------------------------------
__device__ double g_WC[NK * SEQ];                          // 64 KB
__device__ double g_Bk[NK];                                // 64 B
__device__ __align__(16) float g_Wt[SEQ * DM];             // 1 MB  [s][d]
__device__ __align__(16) float g_zp[4 * BS * NV * DM];     // 33.5 MB [kblk][b][v][d]
__device__ double g_nn2[BS * NV];                          // 64 KB
__device__ double g_Dp[8 * BS * NV * NK];                  // 4 MB [sc][b][v][k]
__device__ unsigned char g_bits[BS * NV];                  // 8 KB

// ---------------------------------------------------------------------------
// Exact JAX threefry2x32 (20 rounds), key = PRNGKey(7) = (0, 7).
// ---------------------------------------------------------------------------
__device__ __forceinline__ void threefry2x32_key7(uint32_t x0, uint32_t x1,
                                                  uint32_t& o0, uint32_t& o1) {
    const uint32_t k0 = 0u, k1 = 7u;
    const uint32_t k2 = k0 ^ k1 ^ 0x1BD11BDAu;
    uint32_t v0 = x0 + k0, v1 = x1 + k1;
#define TF_ROUND(r) { v0 += v1; v1 = (v1 << (r)) | (v1 >> (32 - (r))); v1 ^= v0; }
    TF_ROUND(13) TF_ROUND(15) TF_ROUND(26) TF_ROUND(6)
    v0 += k1; v1 += k2 + 1u;
    TF_ROUND(17) TF_ROUND(29) TF_ROUND(16) TF_ROUND(24)
    v0 += k2; v1 += k0 + 2u;
    TF_ROUND(13) TF_ROUND(15) TF_ROUND(26) TF_ROUND(6)
    v0 += k0; v1 += k1 + 3u;
    TF_ROUND(17) TF_ROUND(29) TF_ROUND(16) TF_ROUND(24)
    v0 += k1; v1 += k2 + 4u;
    TF_ROUND(13) TF_ROUND(15) TF_ROUND(26) TF_ROUND(6)
    v0 += k2; v1 += k0 + 5u;
#undef TF_ROUND
    o0 = v0; o1 = v1;
}

__device__ __forceinline__ float bits_to_uniform(uint32_t b) {
    return __uint_as_float((b >> 9) | 0x3F800000u) - 1.0f;
}

// ---------------------------------------------------------------------------
// Merged W-transpose + prep (independent outputs, one dispatch, 64 blocks).
// Blocks 0..31: g_Wt[s][d] = W[d][s] (64s x 128d LDS tiles, both coalesced).
// Blocks 32..63: WC, Bk in fp64 (identical to proven prep_kernel).
// ---------------------------------------------------------------------------
__global__ __launch_bounds__(256) void prep_merged_kernel(
        const float* __restrict__ W, const float* __restrict__ bias,
        const float* __restrict__ ce) {
    __shared__ float tile[64][132];
    __shared__ double red[256];
    __shared__ double cen[256];
    const int t = threadIdx.x;
    const int bid = blockIdx.x;

    if (bid < 32) {
        const int s0 = (bid & 15) * 64;
        const int d0 = (bid >> 4) * 128;
#pragma unroll
        for (int p = 0; p < 32; ++p) {
            int lin = p * 256 + t;
            int d = lin >> 6, s = lin & 63;          // read coalesced over s
            tile[s][d] = W[(size_t)(d0 + d) * SEQ + s0 + s];
        }
        __syncthreads();
#pragma unroll
        for (int p = 0; p < 32; ++p) {
            int lin = p * 256 + t;
            int s = lin >> 7, d = lin & 127;         // write coalesced over d
            g_Wt[(size_t)(s0 + s) * DM + d0 + d] = tile[s][d];
        }
        return;
    }

    const int pid = bid - 32;
    const int k = pid >> 2;
    const int schunk = pid & 3;

    double c = (double)ce[k * DM + t];
    red[t] = c * c;
    __syncthreads();
    for (int off = 128; off > 0; off >>= 1) {
        if (t < off) red[t] += red[t + off];
        __syncthreads();
    }
    double nc = fmax(sqrt(red[0]), 1e-12);
    cen[t] = c / nc;
    __syncthreads();
    red[t] = (double)bias[t] * cen[t];
    __syncthreads();
    for (int off = 128; off > 0; off >>= 1) {
        if (t < off) red[t] += red[t + off];
        __syncthreads();
    }
    if (t == 0 && schunk == 0) g_Bk[k] = red[0];

    const int s = schunk * 256 + t;
    double acc = 0.0;
#pragma unroll 8
    for (int d = 0; d < DM; ++d)
        acc += cen[d] * (double)W[(size_t)d * SEQ + s];
    g_WC[(size_t)k * SEQ + s] = acc;
}

// ---------------------------------------------------------------------------
// GEMM (proven 128v x 256d tile, kblk=4 cross-block K-split, thread tile
// 8v x 16d) + two additions:
//  (a) T14 register double-buffer: issue chunk c+1's 12 global float4 loads
//      into registers BEFORE the MAC phase of chunk c, ds_write them to the
//      alternate LDS buffer AFTER -> HBM/L2 latency hides under the 8K-cycle
//      compute phase (we run 1 block/CU = 1 wave/SIMD, so there is no TLP;
//      this ILP split is the only latency hiding available).
//  (b) dkern folded in: per staged 32-s chunk, threads (vv = t&127,
//      kh = t>>7) accumulate fp64 D-partials from the SAME staged xs in the
//      EXACT order of the old dkern (local fp64 sum over the 32-s chunk,
//      then chunk sums added in s-order == dw[0]+dw[1]+dw[2]+dw[3]).
//      Eliminates a 1024-block kernel + a 32 MB x re-read.
// LDS: 2*16.9 (xs) + 2*40.96 (wst) + 16.4 (WC) = 129 KB -> 1 block/CU.
// ---------------------------------------------------------------------------
#define KC 32
#define XS_LD 132           // 128 + 4
#define WST_LD 320          // 16 groups x (16 + 4 pad)

__global__ __launch_bounds__(256, 1) void gemm_kernel(
        const float* __restrict__ x) {
    __shared__ __align__(16) float xs[2][KC * XS_LD];    // 2 x 16.9 KB
    __shared__ __align__(16) float wst[2][KC * WST_LD];  // 2 x 40.96 KB
    __shared__ double wcs[NK * 256];                     // 16.4 KB

    const int t = threadIdx.x;
    const int kblk = blockIdx.x;    // 0..3
    const int vblk = blockIdx.y;    // 0..3
    const int b    = blockIdx.z;    // 0..15
    const int v0 = vblk * 128;
    const float* xb = x + (size_t)b * SEQ * NV;

    const int tv8  = (t & 15) * 8;       // v offset (8 rows)
    const int grp  = t >> 4;             // 0..15 -> d group of 16
    const int td16 = grp * 16;           // d offset
    const int wofs = grp * 20;           // padded LDS offset of the group
    const int sbeg = kblk * 256;

    // D-phase ownership: vv = owned v row, kh = which 4 of the 8 k's.
    const int vv = t & 127;
    const int kh = t >> 7;

    // Stage WC for this kblk's s-range (8 k x 256 s doubles), coalesced.
#pragma unroll
    for (int j = 0; j < 8; ++j) {
        int idx = j * 256 + t;
        wcs[idx] = g_WC[(size_t)(idx >> 8) * SEQ + sbeg + (idx & 255)];
    }

    float acc[8][16];
#pragma unroll
    for (int j = 0; j < 8; ++j)
#pragma unroll
        for (int i = 0; i < 16; ++i) acc[j][i] = 0.0f;

    double Dl[2][4];
#pragma unroll
    for (int h = 0; h < 2; ++h)
#pragma unroll
        for (int j = 0; j < 4; ++j) Dl[h][j] = 0.0;

    float4 rx[4], rw[8];

#define LOADCHUNK(S0)                                                          \
    {                                                                          \
        _Pragma("unroll")                                                      \
        for (int j = 0; j < 4; ++j) {                                          \
            int lin = j * 256 + t;                                             \
            int sl = lin >> 5, c4 = (lin & 31) << 2;                           \
            rx[j] = *(const float4*)&xb[(size_t)((S0) + sl) * NV + v0 + c4];   \
        }                                                                      \
        _Pragma("unroll")                                                      \
        for (int j = 0; j < 8; ++j) {                                          \
            int lin = j * 256 + t;                                             \
            int sl = lin >> 6, c4 = (lin & 63) << 2;                           \
            rw[j] = *(const float4*)&g_Wt[(size_t)((S0) + sl) * DM + c4];      \
        }                                                                      \
    }

#define WRITECHUNK(BUF)                                                        \
    {                                                                          \
        _Pragma("unroll")                                                      \
        for (int j = 0; j < 4; ++j) {                                          \
            int lin = j * 256 + t;                                             \
            int sl = lin >> 5, c4 = (lin & 31) << 2;                           \
            *(float4*)&xs[BUF][sl * XS_LD + c4] = rx[j];                       \
        }                                                                      \
        _Pragma("unroll")                                                      \
        for (int j = 0; j < 8; ++j) {                                          \
            int lin = j * 256 + t;                                             \
            int sl = lin >> 6, c4 = (lin & 63) << 2;                           \
            *(float4*)&wst[BUF][sl * WST_LD + (c4 >> 4) * 20 + (c4 & 15)] = rw[j]; \
        }                                                                      \
    }

    // Prologue: chunk 0 into buf 0.
    LOADCHUNK(sbeg)
    WRITECHUNK(0)
    __syncthreads();

    for (int c = 0; c < 8; ++c) {
        const int buf = c & 1;
        if (c < 7) LOADCHUNK(sbeg + (c + 1) * KC)   // in flight during compute

        // MAC phase on buf (unchanged proven inner loop).
#pragma unroll
        for (int kk = 0; kk < KC; ++kk) {
            const float* xr = &xs[buf][kk * XS_LD + tv8];
            const float* wr = &wst[buf][kk * WST_LD + wofs];
            float4 xv0 = *(const float4*)(xr);
            float4 xv1 = *(const float4*)(xr + 4);
            float4 wv0 = *(const float4*)(wr);
            float4 wv1 = *(const float4*)(wr + 4);
            float4 wv2 = *(const float4*)(wr + 8);
            float4 wv3 = *(const float4*)(wr + 12);
            float xv[8] = {xv0.x, xv0.y, xv0.z, xv0.w, xv1.x, xv1.y, xv1.z, xv1.w};
            float wv[16] = {wv0.x, wv0.y, wv0.z, wv0.w, wv1.x, wv1.y, wv1.z, wv1.w,
                            wv2.x, wv2.y, wv2.z, wv2.w, wv3.x, wv3.y, wv3.z, wv3.w};
#pragma unroll
            for (int j = 0; j < 8; ++j)
#pragma unroll
                for (int i = 0; i < 16; ++i) acc[j][i] += xv[j] * wv[i];
        }

        // D phase on the same staged chunk: local fp64 over 32 s (sequential,
        // == dkern's dw_w), then added to the running sc sum in s-order.
        {
            double loc0 = 0.0, loc1 = 0.0, loc2 = 0.0, loc3 = 0.0;
            const double* wk = &wcs[(kh * 4) * 256 + c * KC];
#pragma unroll 4
            for (int sl = 0; sl < KC; ++sl) {
                double xv = (double)xs[buf][sl * XS_LD + vv];
                loc0 += xv * wk[sl];
                loc1 += xv * wk[256 + sl];
                loc2 += xv * wk[512 + sl];
                loc3 += xv * wk[768 + sl];
            }
            const int h = c >> 2;
            Dl[h][0] += loc0;
            Dl[h][1] += loc1;
            Dl[h][2] += loc2;
            Dl[h][3] += loc3;
        }

        if (c < 7) WRITECHUNK(buf ^ 1)   // implicit vmcnt wait lands here
        __syncthreads();
    }
#undef LOADCHUNK
#undef WRITECHUNK

    // Epilogue 1: fp32 z-partials for this kblk (identical to baseline).
#pragma unroll
    for (int j = 0; j < 8; ++j) {
        size_t base = (size_t)kblk * (BS * NV * DM) +
                      ((size_t)b * NV + v0 + tv8 + j) * DM + td16;
#pragma unroll
        for (int m = 0; m < 16; m += 4)
            *(float4*)&g_zp[base + m] =
                make_float4(acc[j][m], acc[j][m + 1], acc[j][m + 2], acc[j][m + 3]);
    }

    // Epilogue 2: D partials, same layout/values as old dkern.
#pragma unroll
    for (int h = 0; h < 2; ++h) {
        size_t base = (((size_t)(kblk * 2 + h) * BS + b) * NV + v0 + vv) * NK + kh * 4;
#pragma unroll
        for (int j = 0; j < 4; ++j)
            g_Dp[base + j] = Dl[h][j];
    }
}

// ---------------------------------------------------------------------------
// Combine (proven baseline): z = fp64 sum of 4 kblk partials + bias;
// nn2 = sum_d z^2. Grid (vg 32, b 16) = 512 blocks.
// ---------------------------------------------------------------------------
__global__ __launch_bounds__(256) void combine_kernel(
        const float* __restrict__ bias) {
    __shared__ double red[16][17];
    const int t = threadIdx.x;
    const int vg = blockIdx.x;   // 0..31
    const int b  = blockIdx.y;   // 0..15
    const int vl = t >> 4, dg = t & 15;
    const int v = vg * 16 + vl;

    const size_t bvbase = ((size_t)b * NV + v) * DM + dg * 16;
    double sq = 0.0;
#pragma unroll
    for (int m = 0; m < 16; m += 4) {
        float4 p0 = *(const float4*)&g_zp[(size_t)0 * (BS * NV * DM) + bvbase + m];
        float4 p1 = *(const float4*)&g_zp[(size_t)1 * (BS * NV * DM) + bvbase + m];
        float4 p2 = *(const float4*)&g_zp[(size_t)2 * (BS * NV * DM) + bvbase + m];
        float4 p3 = *(const float4*)&g_zp[(size_t)3 * (BS * NV * DM) + bvbase + m];
        float4 bb = *(const float4*)&bias[dg * 16 + m];
        double z0 = (double)p0.x + (double)p1.x + (double)p2.x + (double)p3.x + (double)bb.x;
        double z1 = (double)p0.y + (double)p1.y + (double)p2.y + (double)p3.y + (double)bb.y;
        double z2 = (double)p0.z + (double)p1.z + (double)p2.z + (double)p3.z + (double)bb.z;
        double z3 = (double)p0.w + (double)p1.w + (double)p2.w + (double)p3.w + (double)bb.w;
        sq += z0 * z0 + z1 * z1 + z2 * z2 + z3 * z3;
    }
    red[vl][dg] = sq;
    __syncthreads();
    if (dg == 0) {
        double s = 0.0;
#pragma unroll
        for (int i = 0; i < 16; ++i) s += red[vl][i];
        g_nn2[b * NV + v] = s;
    }
}

// ---------------------------------------------------------------------------
// Finalize (unchanged): sinkhorn softmax fp64, partitionable threefry, bits.
// ---------------------------------------------------------------------------
__global__ __launch_bounds__(256) void finalize_kernel() {
    const int bv = blockIdx.x * 256 + threadIdx.x;   // 0..8191
    double n = fmax(sqrt(g_nn2[bv]), 1e-12);

    double D[NK];
#pragma unroll
    for (int k = 0; k < NK; ++k) D[k] = g_Bk[k];
#pragma unroll
    for (int sc = 0; sc < 8; ++sc) {
#pragma unroll
        for (int k = 0; k < NK; ++k)
            D[k] += g_Dp[((size_t)sc * (BS * NV) + bv) * NK + k];
    }

    double p[NK], sum = 0.0;
#pragma unroll
    for (int k = 0; k < NK; ++k) {
        p[k] = exp((D[k] / n) / 0.05);
        sum += p[k];
    }
    unsigned int byte = 0;
#pragma unroll
    for (int k = 0; k < NK; ++k) {
        uint32_t i = (uint32_t)(k * (BS * NV) + bv);
        uint32_t y0, y1;
        threefry2x32_key7(0u, i, y0, y1);
        float u = bits_to_uniform(y0 ^ y1);
        if ((double)u < p[k] / sum) byte |= 1u << k;
    }
    g_bits[bv] = (unsigned char)byte;
}

// ---------------------------------------------------------------------------
// Write (unchanged): 268 MB broadcast, float4 stores — at HBM floor.
// ---------------------------------------------------------------------------
__global__ __launch_bounds__(256) void write_kernel(float* __restrict__ out) {
    const int t = threadIdx.x;
    const size_t r0 = (size_t)blockIdx.x * 8;
#pragma unroll
    for (int j = 0; j < 8; ++j) {
        size_t r = r0 + j;                      // r = (k*16+b)*512+v
        unsigned int bv = (unsigned int)(r & 8191u);
        unsigned int k  = (unsigned int)(r >> 13);
        float v = ((g_bits[bv] >> k) & 1u) ? 1.0f : 0.0f;
        float4 val = make_float4(v, v, v, v);
        ((float4*)(out + r * 1024))[t] = val;
    }
}

// ---------------------------------------------------------------------------
extern "C" void kernel_launch(void* const* d_in, const int* in_sizes, int n_in,
                              void* d_out, int out_size, void* d_ws, size_t ws_size,
                              hipStream_t stream) {
    const float* x    = (const float*)d_in[0];
    const float* W    = (const float*)d_in[1];
    const float* bias = (const float*)d_in[2];
    const float* ce   = (const float*)d_in[3];
    float* out = (float*)d_out;

    prep_merged_kernel<<<dim3(64), dim3(256), 0, stream>>>(W, bias, ce);
    gemm_kernel<<<dim3(4, 4, 16), dim3(256), 0, stream>>>(x);
    combine_kernel<<<dim3(32, 16), dim3(256), 0, stream>>>(bias);
    finalize_kernel<<<dim3(32), dim3(256), 0, stream>>>();
    write_kernel<<<dim3(8192), dim3(256), 0, stream>>>(out);
}

// Round 3
// 387.764 us; speedup vs baseline: 2.0522x; 2.0522x over previous
//
#include <hip/hip_runtime.h>
#include <math.h>
#include <stdint.h>

// Problem constants: BS=16, SEQ=1024, NV=512, DM=256, K=8
#define BS 16
#define SEQ 1024
#define NV 512
#define DM 256
#define NK 8

// ---------------------------------------------------------------------------
// Module-global scratch. Every launch fully overwrites before reading
// (stream-ordered producer->consumer), so graph replay is self-contained.
// ---------------------------------------------------------------------------
__device__ double g_WC[NK * SEQ];                          // 64 KB
__device__ double g_Bk[NK];                                // 64 B
__device__ __align__(16) float g_Wt[SEQ * DM];             // 1 MB  [s][d]
__device__ __align__(16) float g_zp[4 * BS * NV * DM];     // 33.5 MB [kblk][b][v][d]
__device__ double g_nn2[BS * NV];                          // 64 KB
__device__ double g_Dp[8 * BS * NV * NK];                  // 4 MB [sc][b][v][k]
__device__ unsigned char g_bits[BS * NV];                  // 8 KB

// ---------------------------------------------------------------------------
// Exact JAX threefry2x32 (20 rounds), key = PRNGKey(7) = (0, 7).
// ---------------------------------------------------------------------------
__device__ __forceinline__ void threefry2x32_key7(uint32_t x0, uint32_t x1,
                                                  uint32_t& o0, uint32_t& o1) {
    const uint32_t k0 = 0u, k1 = 7u;
    const uint32_t k2 = k0 ^ k1 ^ 0x1BD11BDAu;
    uint32_t v0 = x0 + k0, v1 = x1 + k1;
#define TF_ROUND(r) { v0 += v1; v1 = (v1 << (r)) | (v1 >> (32 - (r))); v1 ^= v0; }
    TF_ROUND(13) TF_ROUND(15) TF_ROUND(26) TF_ROUND(6)
    v0 += k1; v1 += k2 + 1u;
    TF_ROUND(17) TF_ROUND(29) TF_ROUND(16) TF_ROUND(24)
    v0 += k2; v1 += k0 + 2u;
    TF_ROUND(13) TF_ROUND(15) TF_ROUND(26) TF_ROUND(6)
    v0 += k0; v1 += k1 + 3u;
    TF_ROUND(17) TF_ROUND(29) TF_ROUND(16) TF_ROUND(24)
    v0 += k1; v1 += k2 + 4u;
    TF_ROUND(13) TF_ROUND(15) TF_ROUND(26) TF_ROUND(6)
    v0 += k2; v1 += k0 + 5u;
#undef TF_ROUND
    o0 = v0; o1 = v1;
}

__device__ __forceinline__ float bits_to_uniform(uint32_t b) {
    return __uint_as_float((b >> 9) | 0x3F800000u) - 1.0f;
}

// ---------------------------------------------------------------------------
// Merged W-transpose + prep (proven in rounds 1-2). 64 blocks.
// Blocks 0..31: g_Wt[s][d] = W[d][s] (64s x 128d LDS tiles, both coalesced).
// Blocks 32..63: WC, Bk in fp64 (identical FP order to original prep).
// ---------------------------------------------------------------------------
__global__ __launch_bounds__(256) void prep_merged_kernel(
        const float* __restrict__ W, const float* __restrict__ bias,
        const float* __restrict__ ce) {
    __shared__ float tile[64][132];
    __shared__ double red[256];
    __shared__ double cen[256];
    const int t = threadIdx.x;
    const int bid = blockIdx.x;

    if (bid < 32) {
        const int s0 = (bid & 15) * 64;
        const int d0 = (bid >> 4) * 128;
#pragma unroll
        for (int p = 0; p < 32; ++p) {
            int lin = p * 256 + t;
            int d = lin >> 6, s = lin & 63;          // read coalesced over s
            tile[s][d] = W[(size_t)(d0 + d) * SEQ + s0 + s];
        }
        __syncthreads();
#pragma unroll
        for (int p = 0; p < 32; ++p) {
            int lin = p * 256 + t;
            int s = lin >> 7, d = lin & 127;         // write coalesced over d
            g_Wt[(size_t)(s0 + s) * DM + d0 + d] = tile[s][d];
        }
        return;
    }

    const int pid = bid - 32;
    const int k = pid >> 2;
    const int schunk = pid & 3;

    double c = (double)ce[k * DM + t];
    red[t] = c * c;
    __syncthreads();
    for (int off = 128; off > 0; off >>= 1) {
        if (t < off) red[t] += red[t + off];
        __syncthreads();
    }
    double nc = fmax(sqrt(red[0]), 1e-12);
    cen[t] = c / nc;
    __syncthreads();
    red[t] = (double)bias[t] * cen[t];
    __syncthreads();
    for (int off = 128; off > 0; off >>= 1) {
        if (t < off) red[t] += red[t + off];
        __syncthreads();
    }
    if (t == 0 && schunk == 0) g_Bk[k] = red[0];

    const int s = schunk * 256 + t;
    double acc = 0.0;
#pragma unroll 8
    for (int d = 0; d < DM; ++d)
        acc += cen[d] * (double)W[(size_t)d * SEQ + s];
    g_WC[(size_t)k * SEQ + s] = acc;
}

// ---------------------------------------------------------------------------
// GEMM, occupancy-fixed: block tile 64v x 256d, thread tile 8v x 8d (64 acc),
// kblk=4 cross-block K-split (g_zp layout & FP order IDENTICAL to baseline).
// Grid (kblk 4, vblk 8, b 16) = 512 blocks = 2 blocks/CU; LDS 42.5 KB and
// __launch_bounds__(256,2) (VGPR<=128, no spill) so TWO independent blocks
// co-reside per CU: while one block is in its stage/barrier phase the other
// issues FMAs. Round-2's reg-dbuf (VGPR 256 -> 1.7 GB scratch) is removed;
// round-0's 1-wave/SIMD latency exposure is fixed by TLP instead of ILP.
// ---------------------------------------------------------------------------
#define KC 32
#define XS_LD 68            // 64 + 4
#define WST_LD 264          // 256 + 8

__global__ __launch_bounds__(256, 2) void gemm_kernel(
        const float* __restrict__ x) {
    __shared__ __align__(16) float xs[KC * XS_LD];     // 8.7 KB
    __shared__ __align__(16) float wst[KC * WST_LD];   // 33.8 KB

    const int t = threadIdx.x;
    const int kblk = blockIdx.x;    // 0..3
    const int vblk = blockIdx.y;    // 0..7
    const int b    = blockIdx.z;    // 0..15
    const int v0 = vblk * 64;
    const float* xb = x + (size_t)b * SEQ * NV;

    const int tv8 = (t & 7) * 8;         // v offset (8 rows)
    const int grp = t >> 3;              // 0..31 -> d group of 8
    const int td8 = grp * 8;             // d offset

    float acc[8][8];
#pragma unroll
    for (int j = 0; j < 8; ++j)
#pragma unroll
        for (int i = 0; i < 8; ++i) acc[j][i] = 0.0f;

    const int sbeg = kblk * 256;
    for (int s0 = sbeg; s0 < sbeg + 256; s0 += KC) {
        __syncthreads();
        // stage x: 32 s x 64 v = 512 float4, 2 per thread
#pragma unroll
        for (int j = 0; j < 2; ++j) {
            int lin = j * 256 + t;
            int sl = lin >> 4, c4 = (lin & 15) << 2;
            float4 val = *(const float4*)&xb[(size_t)(s0 + sl) * NV + v0 + c4];
            *(float4*)&xs[sl * XS_LD + c4] = val;
        }
        // stage Wt: 32 s x 256 d = 2048 float4, 8 per thread
#pragma unroll
        for (int j = 0; j < 8; ++j) {
            int lin = j * 256 + t;
            int sl = lin >> 6, c4 = (lin & 63) << 2;
            float4 val = *(const float4*)&g_Wt[(size_t)(s0 + sl) * DM + c4];
            *(float4*)&wst[sl * WST_LD + c4] = val;
        }
        __syncthreads();
#pragma unroll
        for (int kk = 0; kk < KC; ++kk) {
            const float* xr = &xs[kk * XS_LD + tv8];
            const float* wr = &wst[kk * WST_LD + td8];
            float4 xv0 = *(const float4*)(xr);
            float4 xv1 = *(const float4*)(xr + 4);
            float4 wv0 = *(const float4*)(wr);
            float4 wv1 = *(const float4*)(wr + 4);
            float xv[8] = {xv0.x, xv0.y, xv0.z, xv0.w, xv1.x, xv1.y, xv1.z, xv1.w};
            float wv[8] = {wv0.x, wv0.y, wv0.z, wv0.w, wv1.x, wv1.y, wv1.z, wv1.w};
#pragma unroll
            for (int j = 0; j < 8; ++j)
#pragma unroll
                for (int i = 0; i < 8; ++i) acc[j][i] += xv[j] * wv[i];
        }
    }

    // Epilogue: fp32 z-partials for this kblk (same layout as baseline).
#pragma unroll
    for (int j = 0; j < 8; ++j) {
        size_t base = (size_t)kblk * (BS * NV * DM) +
                      ((size_t)b * NV + v0 + tv8 + j) * DM + td8;
#pragma unroll
        for (int m = 0; m < 8; m += 4)
            *(float4*)&g_zp[base + m] =
                make_float4(acc[j][m], acc[j][m + 1], acc[j][m + 2], acc[j][m + 3]);
    }
}

// ---------------------------------------------------------------------------
// Combine (proven baseline): z = fp64 sum of 4 kblk partials + bias;
// nn2 = sum_d z^2. Grid (vg 32, b 16) = 512 blocks.
// ---------------------------------------------------------------------------
__global__ __launch_bounds__(256) void combine_kernel(
        const float* __restrict__ bias) {
    __shared__ double red[16][17];
    const int t = threadIdx.x;
    const int vg = blockIdx.x;   // 0..31
    const int b  = blockIdx.y;   // 0..15
    const int vl = t >> 4, dg = t & 15;
    const int v = vg * 16 + vl;

    const size_t bvbase = ((size_t)b * NV + v) * DM + dg * 16;
    double sq = 0.0;
#pragma unroll
    for (int m = 0; m < 16; m += 4) {
        float4 p0 = *(const float4*)&g_zp[(size_t)0 * (BS * NV * DM) + bvbase + m];
        float4 p1 = *(const float4*)&g_zp[(size_t)1 * (BS * NV * DM) + bvbase + m];
        float4 p2 = *(const float4*)&g_zp[(size_t)2 * (BS * NV * DM) + bvbase + m];
        float4 p3 = *(const float4*)&g_zp[(size_t)3 * (BS * NV * DM) + bvbase + m];
        float4 bb = *(const float4*)&bias[dg * 16 + m];
        double z0 = (double)p0.x + (double)p1.x + (double)p2.x + (double)p3.x + (double)bb.x;
        double z1 = (double)p0.y + (double)p1.y + (double)p2.y + (double)p3.y + (double)bb.y;
        double z2 = (double)p0.z + (double)p1.z + (double)p2.z + (double)p3.z + (double)bb.z;
        double z3 = (double)p0.w + (double)p1.w + (double)p2.w + (double)p3.w + (double)bb.w;
        sq += z0 * z0 + z1 * z1 + z2 * z2 + z3 * z3;
    }
    red[vl][dg] = sq;
    __syncthreads();
    if (dg == 0) {
        double s = 0.0;
#pragma unroll
        for (int i = 0; i < 16; ++i) s += red[vl][i];
        g_nn2[b * NV + v] = s;
    }
}

// ---------------------------------------------------------------------------
// D-kernel (proven baseline): D_k partials over 128-s chunks, fp64.
// Grid: (vblk=8, b=16, sc=8) = 1024 blocks.
// ---------------------------------------------------------------------------
__global__ __launch_bounds__(256) void dkern(const float* __restrict__ x) {
    __shared__ double wcd[NK][128];
    __shared__ double dw[4][64][NK];
    const int t = threadIdx.x;
    const int vblk = blockIdx.x;
    const int b    = blockIdx.y;
    const int sc   = blockIdx.z;
    const int v0 = vblk * 64;
    const int ss = sc * 128;

#pragma unroll
    for (int j = 0; j < 4; ++j) {
        int idx = j * 256 + t;
        ((double*)wcd)[idx] = g_WC[(size_t)(idx >> 7) * SEQ + ss + (idx & 127)];
    }
    __syncthreads();

    const int vl = t & 63, w = t >> 6;
    const float* xp = x + (size_t)b * SEQ * NV + v0 + vl;
    double D[NK];
#pragma unroll
    for (int k = 0; k < NK; ++k) D[k] = 0.0;
    const int sw = w * 32;
    for (int i = 0; i < 32; ++i) {
        int sl = sw + i;
        double xv = (double)xp[(size_t)(ss + sl) * NV];
#pragma unroll
        for (int k = 0; k < NK; ++k) D[k] += xv * wcd[k][sl];
    }
#pragma unroll
    for (int k = 0; k < NK; ++k) dw[w][vl][k] = D[k];
    __syncthreads();

    const int v = t & 63, k2 = (t >> 6) * 2;
#pragma unroll
    for (int j = 0; j < 2; ++j) {
        int k = k2 + j;
        double s = dw[0][v][k] + dw[1][v][k] + dw[2][v][k] + dw[3][v][k];
        g_Dp[(((size_t)sc * BS + b) * NV + v0 + v) * NK + k] = s;
    }
}

// ---------------------------------------------------------------------------
// Finalize (unchanged): sinkhorn softmax fp64, partitionable threefry, bits.
// ---------------------------------------------------------------------------
__global__ __launch_bounds__(256) void finalize_kernel() {
    const int bv = blockIdx.x * 256 + threadIdx.x;   // 0..8191
    double n = fmax(sqrt(g_nn2[bv]), 1e-12);

    double D[NK];
#pragma unroll
    for (int k = 0; k < NK; ++k) D[k] = g_Bk[k];
#pragma unroll
    for (int sc = 0; sc < 8; ++sc) {
#pragma unroll
        for (int k = 0; k < NK; ++k)
            D[k] += g_Dp[((size_t)sc * (BS * NV) + bv) * NK + k];
    }

    double p[NK], sum = 0.0;
#pragma unroll
    for (int k = 0; k < NK; ++k) {
        p[k] = exp((D[k] / n) / 0.05);
        sum += p[k];
    }
    unsigned int byte = 0;
#pragma unroll
    for (int k = 0; k < NK; ++k) {
        uint32_t i = (uint32_t)(k * (BS * NV) + bv);
        uint32_t y0, y1;
        threefry2x32_key7(0u, i, y0, y1);
        float u = bits_to_uniform(y0 ^ y1);
        if ((double)u < p[k] / sum) byte |= 1u << k;
    }
    g_bits[bv] = (unsigned char)byte;
}

// ---------------------------------------------------------------------------
// Write (unchanged): 268 MB broadcast, float4 stores — at HBM floor.
// ---------------------------------------------------------------------------
__global__ __launch_bounds__(256) void write_kernel(float* __restrict__ out) {
    const int t = threadIdx.x;
    const size_t r0 = (size_t)blockIdx.x * 8;
#pragma unroll
    for (int j = 0; j < 8; ++j) {
        size_t r = r0 + j;                      // r = (k*16+b)*512+v
        unsigned int bv = (unsigned int)(r & 8191u);
        unsigned int k  = (unsigned int)(r >> 13);
        float v = ((g_bits[bv] >> k) & 1u) ? 1.0f : 0.0f;
        float4 val = make_float4(v, v, v, v);
        ((float4*)(out + r * 1024))[t] = val;
    }
}

// ---------------------------------------------------------------------------
extern "C" void kernel_launch(void* const* d_in, const int* in_sizes, int n_in,
                              void* d_out, int out_size, void* d_ws, size_t ws_size,
                              hipStream_t stream) {
    const float* x    = (const float*)d_in[0];
    const float* W    = (const float*)d_in[1];
    const float* bias = (const float*)d_in[2];
    const float* ce   = (const float*)d_in[3];
    float* out = (float*)d_out;

    prep_merged_kernel<<<dim3(64), dim3(256), 0, stream>>>(W, bias, ce);
    gemm_kernel<<<dim3(4, 8, 16), dim3(256), 0, stream>>>(x);
    combine_kernel<<<dim3(32, 16), dim3(256), 0, stream>>>(bias);
    dkern<<<dim3(8, 16, 8), dim3(256), 0, stream>>>(x);
    finalize_kernel<<<dim3(32), dim3(256), 0, stream>>>();
    write_kernel<<<dim3(8192), dim3(256), 0, stream>>>(out);
}